// Round 10
// baseline (353.922 us; speedup 1.0000x reference)
//
#include <hip/hip_runtime.h>

namespace {

typedef __attribute__((ext_vector_type(8))) short short8;   // MFMA A/B frag (8 bf16)
typedef __attribute__((ext_vector_type(4))) float floatx4;  // MFMA C/D frag

constexpr int T    = 512;
constexpr int H    = 64;
constexpr int TPB  = 512;   // 8 waves = 2/SIMD (gate-split pairs)
constexpr int MB   = 8;     // 8 batches per block -> 256 blocks = all CUs
constexpr int HBU  = 144;   // h row stride (ushorts): [0,64)=hi, [72,136)=lo
constexpr int LOFF = 72;
constexpr int XSTR = 516;   // xs row stride (floats)
constexpr int FSTR = 68;    // hf32 row stride (floats, head only)

constexpr int DPP_ROR8 = 0x128;  // row_ror:8 -> lane i reads lane (i+8)&15 == i^8

__device__ __forceinline__ ushort f2bf(float x) {  // fp32 -> bf16 RN-even (finite)
  unsigned u = __float_as_uint(x);
  unsigned r = u + 0x7fffu + ((u >> 16) & 1u);
  return (ushort)(r >> 16);
}
__device__ __forceinline__ float bf2f(ushort h) {
  return __uint_as_float(((unsigned)h) << 16);
}
__device__ __forceinline__ float fsig(float x) {
  return __builtin_amdgcn_rcpf(1.0f + __expf(-x));
}
__device__ __forceinline__ float ftanh(float x) {
  return fmaf(-2.0f, __builtin_amdgcn_rcpf(1.0f + __expf(2.0f * x)), 1.0f);
}
__device__ __forceinline__ float swz8(float v) {   // value from lane^8 (row of 16)
  return __int_as_float(__builtin_amdgcn_update_dpp(
      0, __float_as_int(v), DPP_ROR8, 0xf, 0xf, true));
}

// R10: gate-split wave pairs on the verified R9 machinery.
//   Wave wv: tile = wv&3 (units 16*tile..+16), wg = wv>>2.
//   wg=0 computes gates {i,f}; wg=1 computes {g,o}; both for the same (u,b).
//   Col-packed B (verified R9): cols 0-7 = h_hi(b0-7), 8-15 = h_lo(b0-7);
//   per gate d1=Whi chain (2 MFMA), d2=Wlo chain (2 MFMA); 4-term fp32 split
//   via own + swz8(snd) (lane^8 partner-row exchange, verified R9).
//   Lane owns ONE c-state: unit u = 16*tile + 4*kg + 2*nhi + wg, batch n&7.
//   Pair exchange via LDS: wg=0 sends (i,f) of row B, wg=1 sends (g,o) of
//   row A; one extra barrier. Barrier #1 also separates h-reads from
//   h-writes -> single h buffer (no double-buffering).
__global__ __launch_bounds__(TPB, 1)
void lstm_mfma(const float* __restrict__ xg,
               const float* __restrict__ W_ih,
               const float* __restrict__ W_hh,
               const float* __restrict__ b_ih,
               const float* __restrict__ b_hh,
               const float* __restrict__ fc1_w,
               const float* __restrict__ fc1_b,
               const float* __restrict__ fc2_w,
               const float* __restrict__ fc2_b,
               float* __restrict__ out)
{
  __shared__ __align__(16) ushort hs[MB * HBU];   // h (hi | lo regions), single buffer
  __shared__ __align__(16) float  xs[MB * XSTR];
  __shared__ __align__(16) float  hf[MB * FSTR];  // final h fp32 (head; written once)
  __shared__ float2 exA[4][64];   // written by wg=0: (i,f) preacts of row B
  __shared__ float2 exB[4][64];   // written by wg=1: (g,o) preacts of row A
  __shared__ float  zs[MB][16];

  const int tid  = threadIdx.x;
  const int b0   = blockIdx.x * MB;
  const int lane = tid & 63;
  const int wv   = tid >> 6;       // 0..7
  const int tile = wv & 3;         // unit tile
  const int wg   = wv >> 2;        // 0: gates i,f + row A; 1: gates g,o + row B
  const int n    = lane & 15;      // MFMA col; batch = n&7, half = n>>3
  const int kg   = lane >> 4;      // k-group (A/B), row-quad (D)
  const int bat  = n & 7;
  const int nhi  = n >> 3;
  const int roff = 2 * nhi;

  // ---- stage x (coalesced float4) ----
  for (int i = tid; i < MB * T / 4; i += TPB) {
    const int xb = i >> 7, tq = i & 127;
    float4 v = ((const float4*)(xg + (size_t)(b0 + xb) * T))[tq];
    *(float4*)&xs[xb * XSTR + tq * 4] = v;
  }
  // ---- zero h (h0 = 0; pads stay 0) ----
  for (int i = tid; i < MB * HBU; i += TPB) hs[i] = 0;

  // ---- static W fragments: only this wave's 2 gates (layout verified R5/R9) ----
  short8 whi0[2], whi1[2], wlo0[2], wlo1[2];
#pragma unroll
  for (int gg = 0; gg < 2; ++gg) {
    const int g = 2 * wg + gg;
    const int arow = 64 * g + 16 * tile + n;        // this lane's A-frag row
    const float* wr = W_hh + arow * H + 8 * kg;     // k slice [8kg,8kg+8) and +32
    const float4 p0 = *(const float4*)(wr + 0);
    const float4 p1 = *(const float4*)(wr + 4);
    const float4 p2 = *(const float4*)(wr + 32);
    const float4 p3 = *(const float4*)(wr + 36);
    const float v0[8] = {p0.x, p0.y, p0.z, p0.w, p1.x, p1.y, p1.z, p1.w};
    const float v1[8] = {p2.x, p2.y, p2.z, p2.w, p3.x, p3.y, p3.z, p3.w};
#pragma unroll
    for (int j = 0; j < 8; ++j) {
      const ushort h0 = f2bf(v0[j]);
      whi0[gg][j] = (short)h0;
      wlo0[gg][j] = (short)f2bf(v0[j] - bf2f(h0));  // exact remainder, then RN
      const ushort h1 = f2bf(v1[j]);
      whi1[gg][j] = (short)h1;
      wlo1[gg][j] = (short)f2bf(v1[j] - bf2f(h1));
    }
  }
  // bias + W_ih for rows A,B of this wave's 2 gates
  float bia[2][2], wih[2][2];
#pragma unroll
  for (int gg = 0; gg < 2; ++gg) {
    const int drow = 64 * (2 * wg + gg) + 16 * tile + 4 * kg + roff;
#pragma unroll
    for (int j = 0; j < 2; ++j) {
      bia[gg][j] = b_ih[drow + j] + b_hh[drow + j];
      wih[gg][j] = W_ih[drow + j];
    }
  }

  const int rdoff = bat * HBU + LOFF * nhi + 8 * kg;  // B-frag read base
  const int u     = 16 * tile + 4 * kg + roff + wg;   // owned unit
  const int hwhi  = bat * HBU + u;                    // h hi write index
  const float* xq = &xs[bat * XSTR];
  float c = 0.0f, hk = 0.0f;

  __syncthreads();

  for (int t = 0; t < T; ++t) {
    // ---- phase 1: MFMA + col-sum + preacts for this wave's 2 gates ----
    const ushort* hb = hs + rdoff;
    const short8 f0 = *(const short8*)(hb + 0);    // k 0..31  (hi or lo col-half)
    const short8 f1 = *(const short8*)(hb + 32);   // k 32..63
    const floatx4 zf = {0.f, 0.f, 0.f, 0.f};
    const float xt = xq[t];
    float pA[2], pB[2];   // preacts for rows A,B of gates 2wg, 2wg+1
#pragma unroll
    for (int gg = 0; gg < 2; ++gg) {
      floatx4 d1 = __builtin_amdgcn_mfma_f32_16x16x32_bf16(whi0[gg], f0, zf, 0, 0, 0);
      floatx4 d2 = __builtin_amdgcn_mfma_f32_16x16x32_bf16(wlo0[gg], f0, zf, 0, 0, 0);
      d1 = __builtin_amdgcn_mfma_f32_16x16x32_bf16(whi1[gg], f1, d1, 0, 0, 0);
      d2 = __builtin_amdgcn_mfma_f32_16x16x32_bf16(wlo1[gg], f1, d2, 0, 0, 0);
      const float ownA = nhi ? (d1[2] + d2[2]) : (d1[0] + d2[0]);
      const float ownB = nhi ? (d1[3] + d2[3]) : (d1[1] + d2[1]);
      const float sndA = nhi ? (d1[0] + d2[0]) : (d1[2] + d2[2]);
      const float sndB = nhi ? (d1[1] + d2[1]) : (d1[3] + d2[3]);
      pA[gg] = ownA + swz8(sndA) + fmaf(xt, wih[gg][0], bia[gg][0]);
      pB[gg] = ownB + swz8(sndB) + fmaf(xt, wih[gg][1], bia[gg][1]);
    }
    // ---- pair exchange (wave-uniform branch) ----
    if (wg == 0) exA[tile][lane] = make_float2(pB[0], pB[1]);  // send (i,f)(B)
    else         exB[tile][lane] = make_float2(pA[0], pA[1]);  // send (g,o)(A)
    __syncthreads();   // #1: exchange visible; also h-reads done before h-writes
    const float2 rx = wg ? exA[tile][lane] : exB[tile][lane];
    const float pi = wg ? rx.x  : pA[0];
    const float pf = wg ? rx.y  : pA[1];
    const float pg = wg ? pB[0] : rx.x;
    const float po = wg ? pB[1] : rx.y;
    // ---- phase 2: one c-state per lane ----
    const float ig = fsig(pi);
    const float fg = fsig(pf);
    const float gc = ftanh(pg);
    const float og = fsig(po);
    c  = fmaf(fg, c, ig * gc);
    hk = og * ftanh(c);
    const ushort hib = f2bf(hk);
    hs[hwhi]        = hib;
    hs[hwhi + LOFF] = f2bf(hk - bf2f(hib));
    __syncthreads();   // #2: h(t+1) visible for next step's B-frag reads
  }

  // ---- final h (fp32, from registers) -> LDS once; then the head ----
  hf[bat * FSTR + u] = hk;
  __syncthreads();
  if (tid < MB * 16) {
    const int bq = tid >> 4, j2 = tid & 15;   // 8 batches x 16 hidden2
    float s = fc1_b[j2];
    const float* fw = fc1_w + j2 * H;
#pragma unroll
    for (int k = 0; k < H; ++k) s = fmaf(hf[bq * FSTR + k], fw[k], s);
    s = fmaxf(s, 0.0f);
    zs[bq][j2] = s * fc2_w[j2];
  }
  __syncthreads();
  if (tid < MB) {
    float s = fc2_b[0];
#pragma unroll
    for (int j = 0; j < 16; ++j) s += zs[tid][j];
    out[b0 + tid] = s;
  }
}

}  // namespace

extern "C" void kernel_launch(void* const* d_in, const int* in_sizes, int n_in,
                              void* d_out, int out_size, void* d_ws, size_t ws_size,
                              hipStream_t stream) {
  const float* xg    = (const float*)d_in[0];
  const float* W_ih  = (const float*)d_in[1];
  const float* W_hh  = (const float*)d_in[2];
  const float* b_ih  = (const float*)d_in[3];
  const float* b_hh  = (const float*)d_in[4];
  const float* fc1_w = (const float*)d_in[5];
  const float* fc1_b = (const float*)d_in[6];
  const float* fc2_w = (const float*)d_in[7];
  const float* fc2_b = (const float*)d_in[8];
  float* out = (float*)d_out;

  dim3 grid(2048 / MB);   // 256 blocks -> 1 per CU, 8 waves = 2/SIMD
  dim3 block(TPB);
  hipLaunchKernelGGL(lstm_mfma, grid, block, 0, stream,
                     xg, W_ih, W_hh, b_ih, b_hh, fc1_w, fc1_b, fc2_w, fc2_b, out);
}